// Round 6
// baseline (254.691 us; speedup 1.0000x reference)
//
#include <hip/hip_runtime.h>

// Problem constants
constexpr int N = 16, C = 64, H = 128, W = 128, P = H * W;   // P = 16384
constexpr int NL = 256, PK = 1024;                            // 256 windows, 32x32 each

// Workspace layout (float units). Liveness:
//   RA: prb bf16 [nl][64cc][1024px]   (k3 -> k5)           8,388,608 fl
//   RB: x1t bf16 [n][px][64c]         (k1 -> k3)           8,388,608 fl
//   RC: x2t bf16 [n][px][64c]         (k1 -> k5)           8,388,608 fl
constexpr size_t OFF_RA    = 0;
constexpr size_t OFF_RB    = 8388608;
constexpr size_t OFF_RC    = 16777216;
constexpr size_t OFF_SUMS  = 25165824;           // 16384 fp32
constexpr size_t OFF_SCALE = OFF_SUMS  + 16384;  // 16384 fp32
constexpr size_t OFF_WMOD  = OFF_SCALE + 16384;  // 36864 ush = 18432 fl
constexpr size_t OFF_W1L   = OFF_WMOD  + 18432;  // 8192 ush = 4096 fl
constexpr size_t OFF_W3L   = OFF_W1L   + 4096;   // 8192 ush = 4096 fl

typedef short bf16x8 __attribute__((ext_vector_type(8)));
typedef float f32x4  __attribute__((ext_vector_type(4)));

__device__ inline unsigned short f2bf(float f) {
    unsigned u = __float_as_uint(f);
    unsigned r = (u + 0x7FFFu + ((u >> 16) & 1u)) >> 16;
    return (unsigned short)r;
}
__device__ inline float bf2f(unsigned short h) {
    return __uint_as_float(((unsigned)h) << 16);
}

// ---------------------------------------------------------------------------
// K0: weight prep. wmod[tap][cib][64co][32ci] (conv2 merged into center tap),
//     w1lay[cib(2)][128co][32ci], w3lay[cib(4)][64co][32ci]; zero SE sums.
__global__ __launch_bounds__(256) void k0_prep(const float* __restrict__ pos_w,
                                               const float* __restrict__ conv2_w,
                                               const float* __restrict__ w1,
                                               const float* __restrict__ w3,
                                               unsigned short* __restrict__ wmod,
                                               unsigned short* __restrict__ w1lay,
                                               unsigned short* __restrict__ w3lay,
                                               float* __restrict__ sums) {
    int t = blockIdx.x * 256 + threadIdx.x;
    if (t < 36864) {
        int cir = t & 31;
        int co  = (t >> 5) & 63;
        int cib = (t >> 11) & 1;
        int tap = t >> 12;
        int ci  = cib * 32 + cir;
        float v = pos_w[(co * 64 + ci) * 9 + tap];
        if (tap == 4) v += conv2_w[co * 64 + ci];
        wmod[t] = f2bf(v);
    } else if (t < 45056) {
        int u = t - 36864;                 // w1lay: [cib(2)][co(128)][ci32]
        int cir = u & 31;
        int co  = (u >> 5) & 127;
        int cib = u >> 12;
        w1lay[u] = f2bf(w1[co * 64 + cib * 32 + cir]);
    } else if (t < 53248) {
        int u = t - 45056;                 // w3lay: [cib(4)][co(64)][ci32]
        int cir = u & 31;
        int co  = (u >> 5) & 63;
        int cib = u >> 11;
        w3lay[u] = f2bf(w3[co * 128 + cib * 32 + cir]);
    } else {
        sums[t - 53248] = 0.f;
    }
}

// ---------------------------------------------------------------------------
// K1: conv1 (1x1, 64->128) + bias via bf16 MFMA, NO LDS / NO barriers.
// Block: 128 px (one image row), 4 waves x 32 px. B-fragments loaded directly
// from global NCHW: per fragment 8 dword loads, 16 consecutive lanes read 16
// consecutive px (64B-coalesced). Writes x1t / x2t bf16 [n][px][64].
__global__ __launch_bounds__(256) void k1_conv1(const float* __restrict__ x,
                                                const unsigned short* __restrict__ w1lay,
                                                const float* __restrict__ b1,
                                                unsigned short* __restrict__ x1t,
                                                unsigned short* __restrict__ x2t) {
    int bid = blockIdx.x;
    int n   = bid >> 7;
    int px0 = (bid & 127) << 7;
    int t   = threadIdx.x;
    int wave = t >> 6, lane = t & 63;
    int quad = lane >> 4, l16 = lane & 15;
    int pxw = wave * 32;
    const float* xb = x + (size_t)n * 64 * P + px0 + pxw + l16;
    bf16x8 bfr[2][2];
    #pragma unroll
    for (int cib = 0; cib < 2; ++cib) {
        #pragma unroll
        for (int pt = 0; pt < 2; ++pt) {
            unsigned short tmp[8];
            #pragma unroll
            for (int q = 0; q < 8; ++q)
                tmp[q] = f2bf(xb[(size_t)(cib * 32 + quad * 8 + q) * P + pt * 16]);
            bfr[cib][pt] = *(const bf16x8*)tmp;
        }
    }
    f32x4 acc[8][2] = {};
    #pragma unroll
    for (int cib = 0; cib < 2; ++cib) {
        bf16x8 af[8];
        #pragma unroll
        for (int ct = 0; ct < 8; ++ct)
            af[ct] = *(const bf16x8*)(w1lay + ((size_t)(cib * 128 + ct * 16 + l16)) * 32 + quad * 8);
        #pragma unroll
        for (int ct = 0; ct < 8; ++ct)
            #pragma unroll
            for (int pt = 0; pt < 2; ++pt)
                acc[ct][pt] = __builtin_amdgcn_mfma_f32_16x16x32_bf16(af[ct], bfr[cib][pt], acc[ct][pt], 0, 0, 0);
    }
    #pragma unroll
    for (int ct = 0; ct < 8; ++ct) {
        int co0 = ct * 16 + quad * 4;
        float4 bb = *(const float4*)(b1 + co0);
        #pragma unroll
        for (int pt = 0; pt < 2; ++pt) {
            int px = px0 + pxw + pt * 16 + l16;
            ushort4 o;
            o.x = f2bf(acc[ct][pt][0] + bb.x);
            o.y = f2bf(acc[ct][pt][1] + bb.y);
            o.z = f2bf(acc[ct][pt][2] + bb.z);
            o.w = f2bf(acc[ct][pt][3] + bb.w);
            if (co0 < 64)
                *(ushort4*)(x1t + ((size_t)n * P + px) * 64 + co0) = o;
            else
                *(ushort4*)(x2t + ((size_t)n * P + px) * 64 + (co0 - 64)) = o;
        }
    }
}

// ---------------------------------------------------------------------------
// K3: fused adaptive-pool + 3x3 SAME conv (conv2 folded) + biases via MFMA.
// R0 structure (one window x 8 pr-rows, 2-phase 32-ch staging, 21.8 KB LDS,
// measured 56.6us / 0 bank conflicts) + DEEP-ISSUE staging: the chunk loop is
// fully unrolled with all gather loads hoisted into register arrays (issue
// all ~24 loads -> then convert+write), instead of the compiler's per-chunk
// load->use->store schedule (~4 in flight). Numerics bit-identical to R0.
__global__ __launch_bounds__(256) void k3_pool_pr(const unsigned short* __restrict__ x1t,
                                                  const unsigned short* __restrict__ wmod,
                                                  const float* __restrict__ b2,
                                                  const float* __restrict__ posb,
                                                  unsigned short* __restrict__ prb,
                                                  float* __restrict__ sums) {
    __shared__ __align__(16) unsigned short lxs[340 * 32];  // 21760 B
    int bid = blockIdx.x;
    int nl  = bid >> 2;
    int r0  = (bid & 3) * 8;
    int n   = nl >> 4, wl = nl & 15;
    int wi  = wl >> 2, wj = wl & 3;
    int t   = threadIdx.x;
    const unsigned short* xb = x1t + (size_t)n * P * 64;
    int wave = t >> 6, lane = t & 63;
    int quad = lane >> 4, l16 = lane & 15;
    int wrow0 = wave * 2;
    f32x4 acc[4][4] = {};
    #pragma unroll
    for (int cib = 0; cib < 2; ++cib) {
        if (cib) __syncthreads();
        // ---- stage phase cib: 1360 chunks = 340 px x 4 parts of 8 ush ----
        // Issue phase: all loads for up to 6 chunks into registers.
        uint4 LA[6], LB[6], LC[6], LD[6];
        bool ok[6];
        #pragma unroll
        for (int j = 0; j < 6; ++j) {
            int e = t + j * 256;
            int pix = e >> 2, part = e & 3;
            int lr = pix / 34, lc = pix - lr * 34;
            int gr = r0 - 1 + lr, gc = lc - 1;
            bool inb = (e < 1360) && ((unsigned)gr < 32u) && ((unsigned)gc < 32u);
            ok[j] = inb;
            if (inb) {
                int sh = gr + (gr >> 4), sw = gc + (gc >> 4);
                int u = wi * 34 + sh - 4, v = wj * 34 + sw - 4;
                int ra = min(max(u, 0), 127), rb = min(max(u + 1, 0), 127);
                int ca = min(max(v, 0), 127), cb = min(max(v + 1, 0), 127);
                int off = cib * 32 + part * 8;
                LA[j] = *(const uint4*)(xb + (size_t)(ra * 128 + ca) * 64 + off);
                LB[j] = *(const uint4*)(xb + (size_t)(ra * 128 + cb) * 64 + off);
                LC[j] = *(const uint4*)(xb + (size_t)(rb * 128 + ca) * 64 + off);
                LD[j] = *(const uint4*)(xb + (size_t)(rb * 128 + cb) * 64 + off);
            }
        }
        // Drain phase: convert + LDS write.
        #pragma unroll
        for (int j = 0; j < 6; ++j) {
            int e = t + j * 256;
            if (e < 1360) {
                int pix = e >> 2, part = e & 3;
                unsigned short oc[8];
                if (ok[j]) {
                    const unsigned short* a = (const unsigned short*)&LA[j];
                    const unsigned short* b = (const unsigned short*)&LB[j];
                    const unsigned short* c = (const unsigned short*)&LC[j];
                    const unsigned short* d = (const unsigned short*)&LD[j];
                    #pragma unroll
                    for (int q = 0; q < 8; ++q)
                        oc[q] = f2bf(0.25f * (bf2f(a[q]) + bf2f(b[q]) + bf2f(c[q]) + bf2f(d[q])));
                } else {
                    #pragma unroll
                    for (int q = 0; q < 8; ++q) oc[q] = 0;
                }
                *(uint4*)(lxs + pix * 32 + ((part ^ ((pix >> 1) & 3)) * 8)) = *(const uint4*)oc;
            }
        }
        __syncthreads();
        // ---- compute: 9 taps x 16 MFMA ----
        #pragma unroll
        for (int tap = 0; tap < 9; ++tap) {
            int dh = tap / 3, dw = tap % 3;
            bf16x8 af[4], bfr[4];
            #pragma unroll
            for (int ct = 0; ct < 4; ++ct)
                af[ct] = *(const bf16x8*)(wmod + (((tap * 2 + cib) * 64) + ct * 16 + l16) * 32 + quad * 8);
            #pragma unroll
            for (int pt = 0; pt < 4; ++pt) {
                int pix = (wrow0 + (pt >> 1) + dh) * 34 + ((pt & 1) * 16 + l16 + dw);
                bfr[pt] = *(const bf16x8*)(lxs + pix * 32 + ((quad ^ ((pix >> 1) & 3)) * 8));
            }
            #pragma unroll
            for (int ct = 0; ct < 4; ++ct)
                #pragma unroll
                for (int pt = 0; pt < 4; ++pt)
                    acc[ct][pt] = __builtin_amdgcn_mfma_f32_16x16x32_bf16(af[ct], bfr[pt], acc[ct][pt], 0, 0, 0);
        }
    }
    // epilogue: bias, prb write (bf16), SE partial sums
    #pragma unroll
    for (int ct = 0; ct < 4; ++ct) {
        #pragma unroll
        for (int r = 0; r < 4; ++r) {
            int co = ct * 16 + quad * 4 + r;
            float bias = b2[co] + posb[co];
            float s = 0.f;
            #pragma unroll
            for (int pt = 0; pt < 4; ++pt) {
                float v = acc[ct][pt][r] + bias;
                int row = r0 + wrow0 + (pt >> 1);
                int col = (pt & 1) * 16 + l16;
                prb[(size_t)nl * 65536 + co * 1024 + row * 32 + col] = f2bf(v);
                s += v;
            }
            s += __shfl_xor(s, 1);
            s += __shfl_xor(s, 2);
            s += __shfl_xor(s, 4);
            s += __shfl_xor(s, 8);
            if (l16 == 0) atomicAdd(&sums[nl * 64 + co], s);
        }
    }
}

// ---------------------------------------------------------------------------
// K3b: SE, one WAVE per window, all cross-lane via shuffles.
__global__ __launch_bounds__(256) void k3b_se(const float* __restrict__ sums,
                                              const float* __restrict__ w1,
                                              const float* __restrict__ w2,
                                              float* __restrict__ scale) {
    int wv   = (blockIdx.x << 2) + (threadIdx.x >> 6);   // window id, 64 blocks x 4 waves
    int lane = threadIdx.x & 63;
    float m = sums[wv * 64 + lane] * (1.f / 1024.f);
    int h = lane >> 3, sub = lane & 7;
    float p = 0.f;
    #pragma unroll
    for (int k = 0; k < 8; ++k) {
        int ci = sub * 8 + k;
        p += w1[h * 64 + ci] * __shfl(m, ci);
    }
    p += __shfl_xor(p, 1);
    p += __shfl_xor(p, 2);
    p += __shfl_xor(p, 4);
    float hid = fmaxf(p, 0.f);             // valid in all 8 lanes of group h
    float v = 0.f;
    #pragma unroll
    for (int r = 0; r < 8; ++r)
        v += w2[lane * 8 + r] * __shfl(hid, r * 8);
    scale[wv * 64 + lane] = 1.f + 1.f / (1.f + __expf(-v));
}

// ---------------------------------------------------------------------------
// K5: fused unscramble + scale + conv3 (1x1, 128 -> 64 ch) via bf16 MFMA.
// Block: one output row H_ (128 px). att half gathered from prb with SE scale
// applied; x2 half streamed from x2t. MFMA phase: 4 cib x 4 ct x 2 pt.
__global__ __launch_bounds__(256) void k5_conv3(const unsigned short* __restrict__ prb,
                                                const float* __restrict__ scale,
                                                const unsigned short* __restrict__ x2t,
                                                const unsigned short* __restrict__ w3lay,
                                                const float* __restrict__ b3,
                                                float* __restrict__ out) {
    __shared__ __align__(16) unsigned short lxs[128 * 136];  // 34816 B
    int bid = blockIdx.x;
    int n   = bid >> 7;
    int row = bid & 127;                 // H_
    int i   = row >> 5, h2 = row & 31;
    int px0 = row << 7;
    int t   = threadIdx.x;
    // ---- x2 half: ch 64..127, contiguous 16B chunks (1024 total) ----
    const unsigned short* src2 = x2t + ((size_t)n * P + (size_t)row * 128) * 64;
    #pragma unroll
    for (int it = 0; it < 4; ++it) {
        int e = t + it * 256;            // 128 px x 8 parts
        int pix = e >> 3, part = e & 7;
        *(uint4*)(lxs + pix * 136 + 64 + part * 8) = *(const uint4*)(src2 + pix * 64 + part * 8);
    }
    // ---- att half: gather from prb + SE scale (fused former k4) ----
    int c2 = t >> 5, w2 = t & 31;        // c2: channel octet, w2: col within window
    int cc_b = h2 >> 1;
    int hb = (h2 & 1) * 512 + w2 * 16 + i * 4;
    #pragma unroll
    for (int mm = 0; mm < 2; ++mm) {
        int nl = n * 16 + c2 * 2 + mm;
        const unsigned short* pb = prb + (size_t)nl * 65536 + (size_t)cc_b * 1024 + hb;
        const float* sb = scale + nl * 64 + cc_b;
        ushort4 v0 = *(const ushort4*)(pb);
        ushort4 v1 = *(const ushort4*)(pb + 16 * 1024);
        ushort4 v2 = *(const ushort4*)(pb + 32 * 1024);
        ushort4 v3 = *(const ushort4*)(pb + 48 * 1024);
        float s0 = sb[0], s1 = sb[16], s2 = sb[32], s3 = sb[48];
        unsigned short* d = lxs + w2 * 136 + c2 * 8 + mm * 4;
        ushort4 o;
        o.x = f2bf(bf2f(v0.x) * s0); o.y = f2bf(bf2f(v1.x) * s1);
        o.z = f2bf(bf2f(v2.x) * s2); o.w = f2bf(bf2f(v3.x) * s3);
        *(ushort4*)(d) = o;                                  // px = w2
        o.x = f2bf(bf2f(v0.y) * s0); o.y = f2bf(bf2f(v1.y) * s1);
        o.z = f2bf(bf2f(v2.y) * s2); o.w = f2bf(bf2f(v3.y) * s3);
        *(ushort4*)(d + 32 * 136) = o;                       // px = 32 + w2
        o.x = f2bf(bf2f(v0.z) * s0); o.y = f2bf(bf2f(v1.z) * s1);
        o.z = f2bf(bf2f(v2.z) * s2); o.w = f2bf(bf2f(v3.z) * s3);
        *(ushort4*)(d + 64 * 136) = o;                       // px = 64 + w2
        o.x = f2bf(bf2f(v0.w) * s0); o.y = f2bf(bf2f(v1.w) * s1);
        o.z = f2bf(bf2f(v2.w) * s2); o.w = f2bf(bf2f(v3.w) * s3);
        *(ushort4*)(d + 96 * 136) = o;                       // px = 96 + w2
    }
    __syncthreads();
    int wave = t >> 6, lane = t & 63;
    int quad = lane >> 4, l16 = lane & 15;
    int pxw = wave * 32;
    f32x4 acc[4][2] = {};
    #pragma unroll
    for (int cib = 0; cib < 4; ++cib) {
        bf16x8 af[4], bfr[2];
        #pragma unroll
        for (int ct = 0; ct < 4; ++ct)
            af[ct] = *(const bf16x8*)(w3lay + ((size_t)(cib * 64 + ct * 16 + l16)) * 32 + quad * 8);
        #pragma unroll
        for (int pt = 0; pt < 2; ++pt)
            bfr[pt] = *(const bf16x8*)(lxs + (pxw + pt * 16 + l16) * 136 + cib * 32 + quad * 8);
        #pragma unroll
        for (int ct = 0; ct < 4; ++ct)
            #pragma unroll
            for (int pt = 0; pt < 2; ++pt)
                acc[ct][pt] = __builtin_amdgcn_mfma_f32_16x16x32_bf16(af[ct], bfr[pt], acc[ct][pt], 0, 0, 0);
    }
    #pragma unroll
    for (int ct = 0; ct < 4; ++ct) {
        int co0 = ct * 16 + quad * 4;
        float4 bb = *(const float4*)(b3 + co0);
        #pragma unroll
        for (int pt = 0; pt < 2; ++pt) {
            int px = px0 + pxw + pt * 16 + l16;
            const float* bp = (const float*)&bb;
            #pragma unroll
            for (int r = 0; r < 4; ++r)
                out[((size_t)n * 64 + co0 + r) * P + px] = acc[ct][pt][r] + bp[r];
        }
    }
}

// ---------------------------------------------------------------------------
extern "C" void kernel_launch(void* const* d_in, const int* in_sizes, int n_in,
                              void* d_out, int out_size, void* d_ws, size_t ws_size,
                              hipStream_t stream) {
    const float* x       = (const float*)d_in[0];
    const float* conv1_w = (const float*)d_in[1];
    const float* conv1_b = (const float*)d_in[2];
    const float* conv2_w = (const float*)d_in[3];
    const float* conv2_b = (const float*)d_in[4];
    const float* conv3_w = (const float*)d_in[5];
    const float* conv3_b = (const float*)d_in[6];
    const float* pos_w   = (const float*)d_in[7];
    const float* pos_b   = (const float*)d_in[8];
    const float* se_w1   = (const float*)d_in[9];
    const float* se_w2   = (const float*)d_in[10];

    float* ws = (float*)d_ws;
    unsigned short* prb  = (unsigned short*)(ws + OFF_RA);
    unsigned short* x1t  = (unsigned short*)(ws + OFF_RB);
    unsigned short* x2t  = (unsigned short*)(ws + OFF_RC);
    float* sums  = ws + OFF_SUMS;
    float* scale = ws + OFF_SCALE;
    unsigned short* wmod  = (unsigned short*)(ws + OFF_WMOD);
    unsigned short* w1lay = (unsigned short*)(ws + OFF_W1L);
    unsigned short* w3lay = (unsigned short*)(ws + OFF_W3L);

    k0_prep   <<<272,  256, 0, stream>>>(pos_w, conv2_w, conv1_w, conv3_w,
                                         wmod, w1lay, w3lay, sums);
    k1_conv1  <<<2048, 256, 0, stream>>>(x, w1lay, conv1_b, x1t, x2t);
    k3_pool_pr<<<1024, 256, 0, stream>>>(x1t, wmod, conv2_b, pos_b, prb, sums);
    k3b_se    <<<64,   256, 0, stream>>>(sums, se_w1, se_w2, scale);
    k5_conv3  <<<2048, 256, 0, stream>>>(prb, scale, x2t, w3lay, conv3_b, (float*)d_out);
}

// Round 7
// 217.518 us; speedup vs baseline: 1.1709x; 1.1709x over previous
//
#include <hip/hip_runtime.h>

// Problem constants
constexpr int N = 16, C = 64, H = 128, W = 128, P = H * W;   // P = 16384
constexpr int NL = 256, PK = 1024;                            // 256 windows, 32x32 each

// Workspace layout (float units). Liveness:
//   RA: prb bf16 [nl][64cc][1024px]   (k3 -> k5)           8,388,608 fl
//   RB: x1t bf16 [n][px][64c]         (k1 -> k3)           8,388,608 fl
//   (x2t eliminated: conv3's x2-half folded to Wf = w3b*W1b applied to x)
constexpr size_t OFF_RA    = 0;
constexpr size_t OFF_RB    = 8388608;
constexpr size_t OFF_SUMS  = 16777216;           // 16384 fp32
constexpr size_t OFF_SCALE = OFF_SUMS  + 16384;  // 16384 fp32
constexpr size_t OFF_WMOD  = OFF_SCALE + 16384;  // 36864 ush = 18432 fl
constexpr size_t OFF_W1L   = OFF_WMOD  + 18432;  // 8192 ush = 4096 fl
constexpr size_t OFF_W3L   = OFF_W1L   + 4096;   // 8192 ush = 4096 fl
constexpr size_t OFF_B3F   = OFF_W3L   + 4096;   // 64 fp32

typedef short bf16x8 __attribute__((ext_vector_type(8)));
typedef float f32x4  __attribute__((ext_vector_type(4)));

__device__ inline unsigned short f2bf(float f) {
    unsigned u = __float_as_uint(f);
    unsigned r = (u + 0x7FFFu + ((u >> 16) & 1u)) >> 16;
    return (unsigned short)r;
}
__device__ inline float bf2f(unsigned short h) {
    return __uint_as_float(((unsigned)h) << 16);
}

// ---------------------------------------------------------------------------
// K0: weight prep. wmod[tap][cib][64co][32ci] (conv2 merged into center tap),
//     w1lay[cib(2)][128co][32ci],
//     w3lay[cib(4)][64co][32ci]: cib 0,1 = w3a (att half);
//                                cib 2,3 = Wf = w3b @ W1b (x2 path folded);
//     b3f[64] = conv3_b + w3b @ b1b; zero SE sums.
__global__ __launch_bounds__(256) void k0_prep(const float* __restrict__ pos_w,
                                               const float* __restrict__ conv2_w,
                                               const float* __restrict__ w1,
                                               const float* __restrict__ w3,
                                               const float* __restrict__ b1,
                                               const float* __restrict__ b3,
                                               unsigned short* __restrict__ wmod,
                                               unsigned short* __restrict__ w1lay,
                                               unsigned short* __restrict__ w3lay,
                                               float* __restrict__ sums,
                                               float* __restrict__ b3f) {
    int t = blockIdx.x * 256 + threadIdx.x;
    if (t < 36864) {
        int cir = t & 31;
        int co  = (t >> 5) & 63;
        int cib = (t >> 11) & 1;
        int tap = t >> 12;
        int ci  = cib * 32 + cir;
        float v = pos_w[(co * 64 + ci) * 9 + tap];
        if (tap == 4) v += conv2_w[co * 64 + ci];
        wmod[t] = f2bf(v);
    } else if (t < 45056) {
        int u = t - 36864;                 // w1lay: [cib(2)][co(128)][ci32]
        int cir = u & 31;
        int co  = (u >> 5) & 127;
        int cib = u >> 12;
        w1lay[u] = f2bf(w1[co * 64 + cib * 32 + cir]);
    } else if (t < 53248) {
        int u = t - 45056;                 // w3lay: [cib(4)][co(64)][ci32]
        int cir = u & 31;
        int co  = (u >> 5) & 63;
        int cib = u >> 11;
        float v;
        if (cib < 2) {
            v = w3[co * 128 + cib * 32 + cir];           // att half, direct
        } else {
            int ci = (cib - 2) * 32 + cir;               // Wf = w3b @ W1b
            v = 0.f;
            #pragma unroll
            for (int k = 0; k < 64; ++k)
                v += w3[co * 128 + 64 + k] * w1[(64 + k) * 64 + ci];
        }
        w3lay[u] = f2bf(v);
    } else if (t < 69632) {
        sums[t - 53248] = 0.f;
    } else if (t < 69696) {
        int co = t - 69632;                // b3f = b3 + w3b @ b1b
        float s = b3[co];
        #pragma unroll
        for (int k = 0; k < 64; ++k)
            s += w3[co * 128 + 64 + k] * b1[64 + k];
        b3f[co] = s;
    }
}

// ---------------------------------------------------------------------------
// K1: conv1 upper half only (1x1, 64->64, x1) + bias via bf16 MFMA.
// NO LDS / NO barriers. Block: 128 px (one image row), 4 waves x 32 px.
// B-fragments loaded directly from global NCHW: per fragment 8 dword loads,
// 16 consecutive lanes read 16 consecutive px (64B-coalesced).
// The x2 half is never materialized (folded into k5 via Wf).
__global__ __launch_bounds__(256) void k1_conv1(const float* __restrict__ x,
                                                const unsigned short* __restrict__ w1lay,
                                                const float* __restrict__ b1,
                                                unsigned short* __restrict__ x1t) {
    int bid = blockIdx.x;
    int n   = bid >> 7;
    int px0 = (bid & 127) << 7;
    int t   = threadIdx.x;
    int wave = t >> 6, lane = t & 63;
    int quad = lane >> 4, l16 = lane & 15;
    int pxw = wave * 32;
    const float* xb = x + (size_t)n * 64 * P + px0 + pxw + l16;
    bf16x8 bfr[2][2];
    #pragma unroll
    for (int cib = 0; cib < 2; ++cib) {
        #pragma unroll
        for (int pt = 0; pt < 2; ++pt) {
            unsigned short tmp[8];
            #pragma unroll
            for (int q = 0; q < 8; ++q)
                tmp[q] = f2bf(xb[(size_t)(cib * 32 + quad * 8 + q) * P + pt * 16]);
            bfr[cib][pt] = *(const bf16x8*)tmp;
        }
    }
    f32x4 acc[4][2] = {};
    #pragma unroll
    for (int cib = 0; cib < 2; ++cib) {
        bf16x8 af[4];
        #pragma unroll
        for (int ct = 0; ct < 4; ++ct)
            af[ct] = *(const bf16x8*)(w1lay + ((size_t)(cib * 128 + ct * 16 + l16)) * 32 + quad * 8);
        #pragma unroll
        for (int ct = 0; ct < 4; ++ct)
            #pragma unroll
            for (int pt = 0; pt < 2; ++pt)
                acc[ct][pt] = __builtin_amdgcn_mfma_f32_16x16x32_bf16(af[ct], bfr[cib][pt], acc[ct][pt], 0, 0, 0);
    }
    #pragma unroll
    for (int ct = 0; ct < 4; ++ct) {
        int co0 = ct * 16 + quad * 4;
        float4 bb = *(const float4*)(b1 + co0);
        #pragma unroll
        for (int pt = 0; pt < 2; ++pt) {
            int px = px0 + pxw + pt * 16 + l16;
            ushort4 o;
            o.x = f2bf(acc[ct][pt][0] + bb.x);
            o.y = f2bf(acc[ct][pt][1] + bb.y);
            o.z = f2bf(acc[ct][pt][2] + bb.z);
            o.w = f2bf(acc[ct][pt][3] + bb.w);
            *(ushort4*)(x1t + ((size_t)n * P + px) * 64 + co0) = o;
        }
    }
}

// ---------------------------------------------------------------------------
// K3: fused adaptive-pool + 3x3 SAME conv (conv2 folded) + biases via MFMA.
// R0/R1-exact structure (measured 56.6us twice, 0 bank conflicts): one window
// x 8 pr-rows, 2 phases of 32 ci, pooled values computed inline in staging.
// LDS 340px x 32ush, XOR-swizzled (chunk' = chunk ^ ((pix>>1)&3)).
__global__ __launch_bounds__(256) void k3_pool_pr(const unsigned short* __restrict__ x1t,
                                                  const unsigned short* __restrict__ wmod,
                                                  const float* __restrict__ b2,
                                                  const float* __restrict__ posb,
                                                  unsigned short* __restrict__ prb,
                                                  float* __restrict__ sums) {
    __shared__ __align__(16) unsigned short lxs[340 * 32];  // 21760 B
    int bid = blockIdx.x;
    int nl  = bid >> 2;
    int r0  = (bid & 3) * 8;
    int n   = nl >> 4, wl = nl & 15;
    int wi  = wl >> 2, wj = wl & 3;
    int t   = threadIdx.x;
    const unsigned short* xb = x1t + (size_t)n * P * 64;
    int wave = t >> 6, lane = t & 63;
    int quad = lane >> 4, l16 = lane & 15;
    int wrow0 = wave * 2;
    f32x4 acc[4][4] = {};
    #pragma unroll
    for (int cib = 0; cib < 2; ++cib) {
        if (cib) __syncthreads();
        // ---- stage phase cib: 1360 chunks = 340 px x 4 parts of 8 ush ----
        for (int it = 0; it < 6; ++it) {
            int e = t + it * 256;
            if (e < 1360) {
                int pix = e >> 2, part = e & 3;
                int lr = pix / 34, lc = pix - lr * 34;
                int gr = r0 - 1 + lr, gc = lc - 1;
                unsigned short oc[8];
                if ((unsigned)gr < 32u && (unsigned)gc < 32u) {
                    int sh = gr + (gr >> 4), sw = gc + (gc >> 4);
                    int u = wi * 34 + sh - 4, v = wj * 34 + sw - 4;
                    int ra = min(max(u, 0), 127), rb = min(max(u + 1, 0), 127);
                    int ca = min(max(v, 0), 127), cb = min(max(v + 1, 0), 127);
                    int off = cib * 32 + part * 8;
                    uint4 A = *(const uint4*)(xb + (size_t)(ra * 128 + ca) * 64 + off);
                    uint4 B = *(const uint4*)(xb + (size_t)(ra * 128 + cb) * 64 + off);
                    uint4 Cc = *(const uint4*)(xb + (size_t)(rb * 128 + ca) * 64 + off);
                    uint4 D = *(const uint4*)(xb + (size_t)(rb * 128 + cb) * 64 + off);
                    const unsigned short* a = (const unsigned short*)&A;
                    const unsigned short* b = (const unsigned short*)&B;
                    const unsigned short* c = (const unsigned short*)&Cc;
                    const unsigned short* d = (const unsigned short*)&D;
                    #pragma unroll
                    for (int q = 0; q < 8; ++q)
                        oc[q] = f2bf(0.25f * (bf2f(a[q]) + bf2f(b[q]) + bf2f(c[q]) + bf2f(d[q])));
                } else {
                    #pragma unroll
                    for (int q = 0; q < 8; ++q) oc[q] = 0;
                }
                *(uint4*)(lxs + pix * 32 + ((part ^ ((pix >> 1) & 3)) * 8)) = *(const uint4*)oc;
            }
        }
        __syncthreads();
        // ---- compute: 9 taps x 16 MFMA ----
        #pragma unroll
        for (int tap = 0; tap < 9; ++tap) {
            int dh = tap / 3, dw = tap % 3;
            bf16x8 af[4], bfr[4];
            #pragma unroll
            for (int ct = 0; ct < 4; ++ct)
                af[ct] = *(const bf16x8*)(wmod + (((tap * 2 + cib) * 64) + ct * 16 + l16) * 32 + quad * 8);
            #pragma unroll
            for (int pt = 0; pt < 4; ++pt) {
                int pix = (wrow0 + (pt >> 1) + dh) * 34 + ((pt & 1) * 16 + l16 + dw);
                bfr[pt] = *(const bf16x8*)(lxs + pix * 32 + ((quad ^ ((pix >> 1) & 3)) * 8));
            }
            #pragma unroll
            for (int ct = 0; ct < 4; ++ct)
                #pragma unroll
                for (int pt = 0; pt < 4; ++pt)
                    acc[ct][pt] = __builtin_amdgcn_mfma_f32_16x16x32_bf16(af[ct], bfr[pt], acc[ct][pt], 0, 0, 0);
        }
    }
    // epilogue: bias, prb write (bf16), SE partial sums
    #pragma unroll
    for (int ct = 0; ct < 4; ++ct) {
        #pragma unroll
        for (int r = 0; r < 4; ++r) {
            int co = ct * 16 + quad * 4 + r;
            float bias = b2[co] + posb[co];
            float s = 0.f;
            #pragma unroll
            for (int pt = 0; pt < 4; ++pt) {
                float v = acc[ct][pt][r] + bias;
                int row = r0 + wrow0 + (pt >> 1);
                int col = (pt & 1) * 16 + l16;
                prb[(size_t)nl * 65536 + co * 1024 + row * 32 + col] = f2bf(v);
                s += v;
            }
            s += __shfl_xor(s, 1);
            s += __shfl_xor(s, 2);
            s += __shfl_xor(s, 4);
            s += __shfl_xor(s, 8);
            if (l16 == 0) atomicAdd(&sums[nl * 64 + co], s);
        }
    }
}

// ---------------------------------------------------------------------------
// K3b: SE, one WAVE per window, all cross-lane via shuffles.
__global__ __launch_bounds__(256) void k3b_se(const float* __restrict__ sums,
                                              const float* __restrict__ w1,
                                              const float* __restrict__ w2,
                                              float* __restrict__ scale) {
    int wv   = (blockIdx.x << 2) + (threadIdx.x >> 6);   // window id, 64 blocks x 4 waves
    int lane = threadIdx.x & 63;
    float m = sums[wv * 64 + lane] * (1.f / 1024.f);
    int h = lane >> 3, sub = lane & 7;
    float p = 0.f;
    #pragma unroll
    for (int k = 0; k < 8; ++k) {
        int ci = sub * 8 + k;
        p += w1[h * 64 + ci] * __shfl(m, ci);
    }
    p += __shfl_xor(p, 1);
    p += __shfl_xor(p, 2);
    p += __shfl_xor(p, 4);
    float hid = fmaxf(p, 0.f);             // valid in all 8 lanes of group h
    float v = 0.f;
    #pragma unroll
    for (int r = 0; r < 8; ++r)
        v += w2[lane * 8 + r] * __shfl(hid, r * 8);
    scale[wv * 64 + lane] = 1.f + 1.f / (1.f + __expf(-v));
}

// ---------------------------------------------------------------------------
// K5: fused unscramble + scale + conv3 via bf16 MFMA, x2 path FOLDED:
// out = w3a . att  +  Wf . x  + b3f. Block: one output row H_ (128 px).
// att half gathered from prb (+SE scale) into LDS [128px][72] (18.4 KB ->
// 8 blocks/CU); x half loaded directly from global fp32 NCHW as MFMA
// fragments (k1's pattern, issued first for latency hiding). No x2t.
__global__ __launch_bounds__(256) void k5_conv3(const unsigned short* __restrict__ prb,
                                                const float* __restrict__ scale,
                                                const float* __restrict__ x,
                                                const unsigned short* __restrict__ w3lay,
                                                const float* __restrict__ b3f,
                                                float* __restrict__ out) {
    __shared__ __align__(16) unsigned short lxs[128 * 72];   // 18432 B
    int bid = blockIdx.x;
    int n   = bid >> 7;
    int row = bid & 127;                 // H_
    int i   = row >> 5, h2 = row & 31;
    int px0 = row << 7;
    int t   = threadIdx.x;
    int wave = t >> 6, lane = t & 63;
    int quad = lane >> 4, l16 = lane & 15;
    int pxw = wave * 32;
    // ---- x half: direct global fp32 fragments (issued first) ----
    const float* xb = x + (size_t)n * 64 * P + px0 + pxw + l16;
    bf16x8 bx[2][2];
    #pragma unroll
    for (int cib = 0; cib < 2; ++cib) {
        #pragma unroll
        for (int pt = 0; pt < 2; ++pt) {
            unsigned short tmp[8];
            #pragma unroll
            for (int q = 0; q < 8; ++q)
                tmp[q] = f2bf(xb[(size_t)(cib * 32 + quad * 8 + q) * P + pt * 16]);
            bx[cib][pt] = *(const bf16x8*)tmp;
        }
    }
    // ---- att half: gather from prb + SE scale into LDS ----
    int c2 = t >> 5, w2 = t & 31;        // c2: channel octet, w2: col within window
    int cc_b = h2 >> 1;
    int hb = (h2 & 1) * 512 + w2 * 16 + i * 4;
    #pragma unroll
    for (int mm = 0; mm < 2; ++mm) {
        int nl = n * 16 + c2 * 2 + mm;
        const unsigned short* pb = prb + (size_t)nl * 65536 + (size_t)cc_b * 1024 + hb;
        const float* sb = scale + nl * 64 + cc_b;
        ushort4 v0 = *(const ushort4*)(pb);
        ushort4 v1 = *(const ushort4*)(pb + 16 * 1024);
        ushort4 v2 = *(const ushort4*)(pb + 32 * 1024);
        ushort4 v3 = *(const ushort4*)(pb + 48 * 1024);
        float s0 = sb[0], s1 = sb[16], s2 = sb[32], s3 = sb[48];
        unsigned short* d = lxs + w2 * 72 + c2 * 8 + mm * 4;
        ushort4 o;
        o.x = f2bf(bf2f(v0.x) * s0); o.y = f2bf(bf2f(v1.x) * s1);
        o.z = f2bf(bf2f(v2.x) * s2); o.w = f2bf(bf2f(v3.x) * s3);
        *(ushort4*)(d) = o;                                  // px = w2
        o.x = f2bf(bf2f(v0.y) * s0); o.y = f2bf(bf2f(v1.y) * s1);
        o.z = f2bf(bf2f(v2.y) * s2); o.w = f2bf(bf2f(v3.y) * s3);
        *(ushort4*)(d + 32 * 72) = o;                        // px = 32 + w2
        o.x = f2bf(bf2f(v0.z) * s0); o.y = f2bf(bf2f(v1.z) * s1);
        o.z = f2bf(bf2f(v2.z) * s2); o.w = f2bf(bf2f(v3.z) * s3);
        *(ushort4*)(d + 64 * 72) = o;                        // px = 64 + w2
        o.x = f2bf(bf2f(v0.w) * s0); o.y = f2bf(bf2f(v1.w) * s1);
        o.z = f2bf(bf2f(v2.w) * s2); o.w = f2bf(bf2f(v3.w) * s3);
        *(ushort4*)(d + 96 * 72) = o;                        // px = 96 + w2
    }
    __syncthreads();
    f32x4 acc[4][2] = {};
    #pragma unroll
    for (int cib = 0; cib < 4; ++cib) {
        bf16x8 af[4], bfr[2];
        #pragma unroll
        for (int ct = 0; ct < 4; ++ct)
            af[ct] = *(const bf16x8*)(w3lay + ((size_t)(cib * 64 + ct * 16 + l16)) * 32 + quad * 8);
        #pragma unroll
        for (int pt = 0; pt < 2; ++pt) {
            if (cib < 2)
                bfr[pt] = *(const bf16x8*)(lxs + (pxw + pt * 16 + l16) * 72 + cib * 32 + quad * 8);
            else
                bfr[pt] = bx[cib - 2][pt];
        }
        #pragma unroll
        for (int ct = 0; ct < 4; ++ct)
            #pragma unroll
            for (int pt = 0; pt < 2; ++pt)
                acc[ct][pt] = __builtin_amdgcn_mfma_f32_16x16x32_bf16(af[ct], bfr[pt], acc[ct][pt], 0, 0, 0);
    }
    #pragma unroll
    for (int ct = 0; ct < 4; ++ct) {
        int co0 = ct * 16 + quad * 4;
        float4 bb = *(const float4*)(b3f + co0);
        #pragma unroll
        for (int pt = 0; pt < 2; ++pt) {
            int px = px0 + pxw + pt * 16 + l16;
            const float* bp = (const float*)&bb;
            #pragma unroll
            for (int r = 0; r < 4; ++r)
                out[((size_t)n * 64 + co0 + r) * P + px] = acc[ct][pt][r] + bp[r];
        }
    }
}

// ---------------------------------------------------------------------------
extern "C" void kernel_launch(void* const* d_in, const int* in_sizes, int n_in,
                              void* d_out, int out_size, void* d_ws, size_t ws_size,
                              hipStream_t stream) {
    const float* x       = (const float*)d_in[0];
    const float* conv1_w = (const float*)d_in[1];
    const float* conv1_b = (const float*)d_in[2];
    const float* conv2_w = (const float*)d_in[3];
    const float* conv2_b = (const float*)d_in[4];
    const float* conv3_w = (const float*)d_in[5];
    const float* conv3_b = (const float*)d_in[6];
    const float* pos_w   = (const float*)d_in[7];
    const float* pos_b   = (const float*)d_in[8];
    const float* se_w1   = (const float*)d_in[9];
    const float* se_w2   = (const float*)d_in[10];

    float* ws = (float*)d_ws;
    unsigned short* prb  = (unsigned short*)(ws + OFF_RA);
    unsigned short* x1t  = (unsigned short*)(ws + OFF_RB);
    float* sums  = ws + OFF_SUMS;
    float* scale = ws + OFF_SCALE;
    unsigned short* wmod  = (unsigned short*)(ws + OFF_WMOD);
    unsigned short* w1lay = (unsigned short*)(ws + OFF_W1L);
    unsigned short* w3lay = (unsigned short*)(ws + OFF_W3L);
    float* b3f   = ws + OFF_B3F;

    k0_prep   <<<273,  256, 0, stream>>>(pos_w, conv2_w, conv1_w, conv3_w,
                                         conv1_b, conv3_b,
                                         wmod, w1lay, w3lay, sums, b3f);
    k1_conv1  <<<2048, 256, 0, stream>>>(x, w1lay, conv1_b, x1t);
    k3_pool_pr<<<1024, 256, 0, stream>>>(x1t, wmod, conv2_b, pos_b, prb, sums);
    k3b_se    <<<64,   256, 0, stream>>>(sums, se_w1, se_w2, scale);
    k5_conv3  <<<2048, 256, 0, stream>>>(prb, scale, x, w3lay, b3f, (float*)d_out);
}